// Round 11
// baseline (7523.917 us; speedup 1.0000x reference)
//
#include <hip/hip_runtime.h>
#include <math.h>

#define TT 2048
#define NB 64
#define EE 256
#define HH 256
#define NGRP 16   // batch groups (4 batches each)
#define PJ 16     // j-partitions (WGs) per group
#define JW 16     // j per WG
#define XLD 288   // swizzled x/h row: 32-float chunk kc at kc*36 (4 pad/chunk)
#define KST 132   // red_s kc stride (2 batches * 64 rows + 4 pad)

__device__ __forceinline__ float sigf(float x) { return 1.f / (1.f + expf(-x)); }

__device__ __forceinline__ unsigned long long packh(unsigned tag, float v) {
    union { float f; unsigned u; } c; c.f = v;
    return ((unsigned long long)tag << 32) | (unsigned long long)c.u;
}

// Persistent grouped LSTM: 256 WGs = 16 batch-groups x 16 j-slices, 1 WG/CU.
// R11: two phase-shifted 2-batch chains per WG (A=b0..b0+1, B=b0+2..b0+3),
// same weight registers serve both. Segment = exact half-width R6 step
// (bit-identical per-(row,batch) numerics). While chain A's publish is in
// flight through the MALL, the WG runs chain B's whole segment -> A's spin
// hits first-try. 3 barriers/segment (pz deferred to next same-chain
// segment). Tagged 64-bit relaxed agent atomics, parity double-buffered.
__global__ __launch_bounds__(256, 1)
void lstm_kernel(const int* __restrict__ sent, const float* __restrict__ emb,
                 const float* __restrict__ W_ih, const float* __restrict__ W_hh,
                 const float* __restrict__ b_ih, const float* __restrict__ b_hh,
                 const float* __restrict__ W_z,
                 unsigned long long* __restrict__ hbuf,
                 float* __restrict__ part)
{
    __shared__ float x_sw[4 * XLD];     // [ch*2+b][XLD]
    __shared__ float h_sw[4 * XLD];     // [ch*2+b][XLD]
    __shared__ float red_s[8 * KST];    // [kc]*132 + [b]*64 + [row]
    __shared__ float g_flat[128];       // [b]*64 + [row]
    __shared__ float p_s[2][32];        // [ch][b*16+jj]
    __shared__ int   tok_ns[2][2];      // [ch][b]

    const int tid  = threadIdx.x;
    // XCD-clustering swizzle (heuristic): group's 16 WGs -> one XCD.
    const int xcd  = blockIdx.x & 7;
    const int slot = blockIdx.x >> 3;       // 0..31
    const int grp  = xcd * 2 + (slot >> 4); // 0..15 batch group
    const int jgrp = slot & 15;             // 0..15 j-slice
    const int b0   = grp << 2;
    const int j0   = jgrp << 4;

    const int wv    = tid >> 6;
    const int lane  = tid & 63;
    const int rg    = lane >> 2;            // 0..15 row-quad (rows rg*4..+3)
    const int klow  = lane & 3;
    const int kc    = (wv >> 1) * 4 + klow; // 0..7 k-chunk (32 floats)
    const int bsg   = wv & 1;               // batch within chain (0..1)
    const int kbase = kc << 5;

    // ---- weights -> VGPR/AGPR: rows rg*4+i over this thread's 32-chunk ----
    float4 wih_r[32], whh_r[32];
    #pragma unroll
    for (int i = 0; i < 4; ++i) {
        int lr_i = rg * 4 + i;
        long grow = (long)((lr_i >> 4) * HH + j0 + (lr_i & 15));
        const float4* wi = (const float4*)(W_ih + grow * EE + kbase);
        const float4* wh = (const float4*)(W_hh + grow * EE + kbase);
        #pragma unroll
        for (int mi = 0; mi < 8; ++mi) {
            wih_r[i * 8 + mi] = wi[mi];
            whh_r[i * 8 + mi] = wh[mi];
        }
    }

    // reduce identity (tid<128): row rrow, batch rb
    const int rrow = tid & 63;
    const int rb   = (tid >> 6) & 1;
    const long grow_r = (long)((rrow >> 4) * HH + j0 + (rrow & 15));
    const float bias_red = b_ih[grow_r] + b_hh[grow_r];

    // gates identity (tid<32): b_e, jj_e ; tid = b_e*16 + jj_e
    const int jj_e = tid & 15;
    const int b_e  = (tid >> 4) & 1;
    const float wz_r = W_z[j0 + jj_e];
    float c_r[2] = {0.f, 0.f};              // cell state per chain

    // spin-fill identity: 2 adjacent slots per thread
    const int cb    = tid >> 7;             // batch within chain
    const int cj    = (tid & 127) << 1;     // j slot (even)
    const int cphys = cj + ((cj >> 5) << 2);

    if (tid < 4) tok_ns[tid >> 1][tid & 1] = sent[0 * NB + b0 + tid];
    __syncthreads();
    {   // prologue: stage x(0) for both chains (4 batches)
        int b  = tid >> 6;                  // 0..3 = ch*2+bl
        int e4 = tid & 63;
        float4 xv = ((const float4*)(emb +
                        (long)tok_ns[b >> 1][b & 1] * EE))[e4];
        int phys = 4 * e4 + ((e4 >> 3) << 2);
        *(float4*)(&x_sw[b * XLD + phys]) = xv;
    }
    __syncthreads();

    for (int t = 0; t < TT; ++t) {
        #pragma unroll
        for (int ch = 0; ch < 2; ++ch) {
            // ---- phase 1: xacc (x_sw staged in this chain's prev segment) ----
            float4 acc[4];
            #pragma unroll
            for (int i = 0; i < 4; ++i) acc[i] = make_float4(0.f, 0.f, 0.f, 0.f);
            {
                const float* xb = &x_sw[(ch * 2 + bsg) * XLD + kc * 36];
                #pragma unroll
                for (int mi = 0; mi < 8; ++mi) {
                    float4 xv4 = *(const float4*)(xb + mi * 4);
                    #pragma unroll
                    for (int i = 0; i < 4; ++i) {
                        float4 w = wih_r[i * 8 + mi];
                        acc[i].x += w.x * xv4.x; acc[i].y += w.y * xv4.y;
                        acc[i].z += w.z * xv4.z; acc[i].w += w.w * xv4.w;
                    }
                }
            }
            const bool pf = (t + 1 < TT);
            if (tid < 2 && pf)
                tok_ns[ch][tid] = sent[(t + 1) * NB + b0 + 2 * ch + tid];

            // deferred pz partial for this chain's previous step
            if (t > 0 && tid < 2) {
                float s = 0.f;
                #pragma unroll
                for (int jl = 0; jl < 16; ++jl) s += p_s[ch][tid * 16 + jl];
                part[((t - 1) * PJ + jgrp) * NB + b0 + 2 * ch + tid] = s;
            }

            // ---- phase 2a: tagged spin-load of this chain's h(t-1) ----
            if (t > 0) {
                const unsigned want = (unsigned)t;
                unsigned long long* hp = hbuf +
                    ((size_t)(((t - 1) & 1) * NB + b0 + 2 * ch + cb)) * HH + cj;
                unsigned long long v0, v1;
                v0 = __hip_atomic_load(hp + 0, __ATOMIC_RELAXED, __HIP_MEMORY_SCOPE_AGENT);
                v1 = __hip_atomic_load(hp + 1, __ATOMIC_RELAXED, __HIP_MEMORY_SCOPE_AGENT);
                while ((unsigned)(v0 >> 32) != want)
                    v0 = __hip_atomic_load(hp + 0, __ATOMIC_RELAXED, __HIP_MEMORY_SCOPE_AGENT);
                while ((unsigned)(v1 >> 32) != want)
                    v1 = __hip_atomic_load(hp + 1, __ATOMIC_RELAXED, __HIP_MEMORY_SCOPE_AGENT);
                union { unsigned u; float f; } c0, c1;
                c0.u = (unsigned)v0; c1.u = (unsigned)v1;
                *(float2*)(&h_sw[(ch * 2 + cb) * XLD + cphys]) =
                    make_float2(c0.f, c1.f);
            }
            __syncthreads();   // B1: h_sw ready; x_sw/p_s reads done

            float4 xv;         // emb prefetch for this chain's x(t+1)
            if (pf && tid < 128) {
                int b  = tid >> 6;
                int e4 = tid & 63;
                xv = ((const float4*)(emb + (long)tok_ns[ch][b] * EE))[e4];
            }

            // ---- phase 2b: hacc into same accumulators ----
            if (t > 0) {
                const float* hb = &h_sw[(ch * 2 + bsg) * XLD + kc * 36];
                #pragma unroll
                for (int mi = 0; mi < 8; ++mi) {
                    float4 hv4 = *(const float4*)(hb + mi * 4);
                    #pragma unroll
                    for (int i = 0; i < 4; ++i) {
                        float4 w = whh_r[i * 8 + mi];
                        acc[i].x += w.x * hv4.x; acc[i].y += w.y * hv4.y;
                        acc[i].z += w.z * hv4.z; acc[i].w += w.w * hv4.w;
                    }
                }
            }
            {   // horizontal add -> red_s (component i = row rg*4+i)
                float4 v;
                v.x = (acc[0].x + acc[0].y) + (acc[0].z + acc[0].w);
                v.y = (acc[1].x + acc[1].y) + (acc[1].z + acc[1].w);
                v.z = (acc[2].x + acc[2].y) + (acc[2].z + acc[2].w);
                v.w = (acc[3].x + acc[3].y) + (acc[3].z + acc[3].w);
                *(float4*)(&red_s[kc * KST + bsg * 64 + rg * 4]) = v;
            }
            if (pf && tid < 128) {   // stage this chain's x(t+1)
                int b  = tid >> 6;
                int e4 = tid & 63;
                int phys = 4 * e4 + ((e4 >> 3) << 2);
                *(float4*)(&x_sw[(ch * 2 + b) * XLD + phys]) = xv;
            }
            __syncthreads();   // B2: red_s + x_sw ready

            // ---- phase 2c: distributed reduce (128 threads) ----
            if (tid < 128) {
                float s = bias_red;
                #pragma unroll
                for (int k2 = 0; k2 < 8; ++k2)
                    s += red_s[k2 * KST + rb * 64 + rrow];
                g_flat[rb * 64 + rrow] = s;
            }
            __syncthreads();   // B3: g_flat ready

            // ---- phase 3: gates + publish (32 threads) ----
            if (tid < 32) {
                float gi = g_flat[b_e * 64 + 0 * 16 + jj_e];
                float gf = g_flat[b_e * 64 + 1 * 16 + jj_e];
                float gg = g_flat[b_e * 64 + 2 * 16 + jj_e];
                float go = g_flat[b_e * 64 + 3 * 16 + jj_e];
                float cn = sigf(gf) * c_r[ch] + sigf(gi) * tanhf(gg);
                float hn = sigf(go) * tanhf(cn);
                c_r[ch] = cn;
                __hip_atomic_store(
                    hbuf + ((size_t)((t & 1) * NB + b0 + 2 * ch + b_e)) * HH
                         + j0 + jj_e,
                    packh((unsigned)(t + 1), hn),
                    __ATOMIC_RELAXED, __HIP_MEMORY_SCOPE_AGENT);
                p_s[ch][tid] = hn * wz_r;
            }
            // no B4: p_s consumed next same-chain segment (pre-B1), ordered
            // by the intervening barriers; g_flat/red_s recycling likewise.
        }
    }
    __syncthreads();           // final p_s flush for t = TT-1
    if (tid < 4) {
        int ch = tid >> 1, k = tid & 1;
        float s = 0.f;
        #pragma unroll
        for (int jl = 0; jl < 16; ++jl) s += p_s[ch][k * 16 + jl];
        part[((TT - 1) * PJ + jgrp) * NB + b0 + 2 * ch + k] = s;
    }
}

__global__ void pz_kernel(const float* __restrict__ part,
                          const float* __restrict__ noise,
                          const float* __restrict__ b_z,
                          float* __restrict__ out)
{
    int idx = blockIdx.x * blockDim.x + threadIdx.x;  // t*64 + b
    if (idx >= TT * NB) return;
    int t = idx >> 6, b = idx & 63;
    float s = b_z[0];
    #pragma unroll
    for (int jg = 0; jg < PJ; ++jg) s += part[(t * PJ + jg) * NB + b];
    float pz = 1.f / (1.f + expf(-s));
    out[idx] = pz;
    out[TT * NB + idx] = (noise[idx] < pz) ? 1.f : 0.f;
}

// One block per batch column: stable compaction of tokens where z==1.
__global__ void compact_kernel(const int* __restrict__ sent,
                               const float* __restrict__ zbuf,
                               float* __restrict__ rat,
                               float* __restrict__ zsz)
{
    __shared__ float rat_s[TT];
    __shared__ int scan_s[256];
    int b = blockIdx.x, tid = threadIdx.x;
    int zloc[8];
    int base = tid * 8;
    int c = 0;
    #pragma unroll
    for (int i = 0; i < 8; ++i) {
        zloc[i] = (zbuf[(base + i) * NB + b] != 0.f) ? 1 : 0;
        c += zloc[i];
    }
    scan_s[tid] = c;
    for (int i = tid; i < TT; i += 256) rat_s[i] = 0.f;
    __syncthreads();
    for (int off = 1; off < 256; off <<= 1) {
        int v = scan_s[tid];
        int add = (tid >= off) ? scan_s[tid - off] : 0;
        __syncthreads();
        scan_s[tid] = v + add;
        __syncthreads();
    }
    int total = scan_s[255];
    int pos = scan_s[tid] - c;  // exclusive prefix
    #pragma unroll
    for (int i = 0; i < 8; ++i) {
        if (zloc[i]) { rat_s[pos] = (float)sent[(base + i) * NB + b]; ++pos; }
    }
    __syncthreads();
    for (int i = tid; i < TT; i += 256) rat[i * NB + b] = rat_s[i];
    if (tid == 0) zsz[b] = (float)total;
}

extern "C" void kernel_launch(void* const* d_in, const int* in_sizes, int n_in,
                              void* d_out, int out_size, void* d_ws, size_t ws_size,
                              hipStream_t stream)
{
    const int*   sent  = (const int*)d_in[0];
    const float* noise = (const float*)d_in[1];
    const float* emb   = (const float*)d_in[2];
    const float* W_ih  = (const float*)d_in[3];
    const float* W_hh  = (const float*)d_in[4];
    const float* b_ih  = (const float*)d_in[5];
    const float* b_hh  = (const float*)d_in[6];
    const float* W_z   = (const float*)d_in[7];
    const float* b_z   = (const float*)d_in[8];
    float* out = (float*)d_out;

    char* ws = (char*)d_ws;
    unsigned long long* hbuf = (unsigned long long*)ws;     // 2*64*256*8 = 256 KB
    float* part = (float*)(ws + 262144);                    // 2048*16*64*4 = 8 MB

    // tags must start != any expected tag (1..2048)
    hipMemsetAsync(hbuf, 0, 2 * NB * HH * sizeof(unsigned long long), stream);

    lstm_kernel<<<256, 256, 0, stream>>>(sent, emb, W_ih, W_hh, b_ih, b_hh, W_z,
                                         hbuf, part);
    pz_kernel<<<(TT * NB) / 256, 256, 0, stream>>>(part, noise, b_z, out);
    compact_kernel<<<NB, 256, 0, stream>>>(sent, out + TT * NB,
                                           out + 2 * TT * NB, out + 3 * TT * NB);
}